// Round 5
// baseline (145.282 us; speedup 1.0000x reference)
//
#include <hip/hip_runtime.h>

// hidden = tanh(x @ (Wi+Wh)^T + (bi+bh)); h_last = hidden[:, -1, :]
// GEMM M=65536 N=256 K=256 fp32 in/out, bf16 MFMA. ~134 MB traffic floor
// (~21 us @ 6.3 TB/s). R5: burst-mode one-shot blocks. Every wave issues ALL
// its global loads (8 W-chunks THEN 16 A-b128) before a sched_barrier(0) so
// the compiler cannot sink them (R3/R4 failure: loads sunk into K-loop,
// ~1KB/wave in flight, 2.6 TB/s). W-LDS writes need only vmcnt(16) since W
// loads are oldest; the single __syncthreads does one bulk drain. Grid 1024 =
// 2 blocks/CU exactly (all co-resident), 16 waves/CU, 128 VGPR cap fully used.

using short8 = __attribute__((ext_vector_type(8))) short;
using f32x4  = __attribute__((ext_vector_type(4))) float;

constexpr int Tn = 4096, Cn = 256, Hn = 256;
constexpr int Mn = 16 * Tn; // 65536

// round-to-nearest-even fp32 -> bf16, two packed into one u32
__device__ inline unsigned pack2_bf16(float a, float b) {
  unsigned ua = __float_as_uint(a);
  unsigned ub = __float_as_uint(b);
  ua += 0x7fffu + ((ua >> 16) & 1u);
  ub += 0x7fffu + ((ub >> 16) & 1u);
  return (ua >> 16) | (ub & 0xffff0000u);
}

union u4s8 { uint4 u; short8 s; };

__global__ __launch_bounds__(256) void prep_kernel(
    const float* __restrict__ Wi, const float* __restrict__ bi,
    const float* __restrict__ Wh, const float* __restrict__ bh,
    unsigned short* __restrict__ Wc, float* __restrict__ bc) {
  int idx = blockIdx.x * 256 + threadIdx.x;
  float w = Wi[idx] + Wh[idx];
  unsigned u = __float_as_uint(w);
  u += 0x7fffu + ((u >> 16) & 1u);
  Wc[idx] = (unsigned short)(u >> 16);
  if (blockIdx.x == 0) bc[threadIdx.x] = bi[threadIdx.x] + bh[threadIdx.x];
}

// 512 thr = 8 waves. Block: 128 rows x 128 cols. Wave: 16 rows x 128 cols.
__global__ __launch_bounds__(512, 4) void gemm_tanh_kernel(
    const float* __restrict__ x, const unsigned short* __restrict__ Wc,
    const float* __restrict__ bc, float* __restrict__ out) {
  // 128 n-rows x 256 k bf16; 16B-chunk XOR swizzle: chunk' = chunk ^ (row&7)
  __shared__ __align__(16) unsigned short Bsm[128 * 256]; // 64 KB

  const int tid   = threadIdx.x;
  const int bid   = blockIdx.x;
  const int mb    = bid & 511;  // n-siblings of an m-block share XCD (512%8==0)
  const int nb    = bid >> 9;
  const int mBase = mb * 128;
  const int nBase = nb * 128;

  const int wave = tid >> 6;   // 0..7 -> 16-row slice
  const int lane = tid & 63;
  const int rid  = lane & 15;  // row/col within 16x16 tile
  const int kgrp = lane >> 4;  // 0..3: k-group of 8
  const int rowBase = mBase + wave * 16;

  // ---- (1) W-half loads FIRST (oldest in vmcnt queue): 8 x 16B per thread
  uint4 wbuf[8];
  int wr[8], wc[8];
#pragma unroll
  for (int i = 0; i < 8; i++) {
    int h = i * 512 + tid; // 0..4095
    wr[i] = h >> 5;        // local n-row 0..127
    wc[i] = h & 31;        // 16B chunk
    wbuf[i] = *(const uint4*)(Wc + (size_t)(nBase + wr[i]) * Cn + wc[i] * 8);
  }

  // ---- (2) the wave's ENTIRE K=256 A-slab: 16 x b128 per lane (64 VGPR)
  const float* ap = x + (size_t)(rowBase + rid) * Cn + kgrp * 8;
  float4 abuf[8][2];
#pragma unroll
  for (int kc = 0; kc < 8; kc++) {
    const float4* p = (const float4*)(ap + kc * 32);
    abuf[kc][0] = p[0];
    abuf[kc][1] = p[1];
  }

  // ---- (3) fence: nothing may cross; loads cannot sink into the K-loop
  __builtin_amdgcn_sched_barrier(0);

  // ---- (4) stage W to LDS (waits vmcnt<=16: A-loads stay in flight)
#pragma unroll
  for (int i = 0; i < 8; i++) {
    int pc = wc[i] ^ (wr[i] & 7);
    *(uint4*)&Bsm[(wr[i] << 8) + (pc << 3)] = wbuf[i];
  }
  __syncthreads(); // the only barrier (bulk vmcnt(0) drain — all loads issued)

  f32x4 acc[8];
#pragma unroll
  for (int in = 0; in < 8; in++) acc[in] = (f32x4)0.f;

#pragma unroll
  for (int kc = 0; kc < 8; kc++) {
    u4s8 t0;
    t0.u.x = pack2_bf16(abuf[kc][0].x, abuf[kc][0].y);
    t0.u.y = pack2_bf16(abuf[kc][0].z, abuf[kc][0].w);
    t0.u.z = pack2_bf16(abuf[kc][1].x, abuf[kc][1].y);
    t0.u.w = pack2_bf16(abuf[kc][1].z, abuf[kc][1].w);
    short8 af = t0.s;

    const int cbase = (kc << 2) | kgrp;
#pragma unroll
    for (int in = 0; in < 8; in++) {
      int ln = in * 16 + rid;
      short8 bf = *(const short8*)&Bsm[(ln << 8) + ((cbase ^ (ln & 7)) << 3)];
      acc[in] = __builtin_amdgcn_mfma_f32_16x16x32_bf16(af, bf, acc[in], 0, 0, 0);
    }
  }

  // ---- epilogue: bias + tanh
#pragma unroll
  for (int in = 0; in < 8; in++) {
    int n = nBase + in * 16 + rid;
    float bias = bc[n];
    int mrow = rowBase + kgrp * 4;
#pragma unroll
    for (int r = 0; r < 4; r++) {
      int m = mrow + r;
      float v = acc[in][r] + bias;
      // tanh(v) = 1 - 2/(exp(2v)+1); overflow -> 1, underflow -> -1
      float t = 1.f - 2.f / (__expf(2.f * v) + 1.f);
      out[(size_t)m * Hn + n] = t;
      if ((m & (Tn - 1)) == (Tn - 1))
        out[(size_t)Mn * Hn + (size_t)(m >> 12) * Hn + n] = t;
    }
  }
}

extern "C" void kernel_launch(void* const* d_in, const int* in_sizes, int n_in,
                              void* d_out, int out_size, void* d_ws,
                              size_t ws_size, hipStream_t stream) {
  (void)in_sizes; (void)n_in; (void)out_size; (void)ws_size;
  const float* x  = (const float*)d_in[0];
  const float* Wi = (const float*)d_in[1];
  const float* bi = (const float*)d_in[2];
  const float* Wh = (const float*)d_in[3];
  const float* bh = (const float*)d_in[4];
  float* out = (float*)d_out;

  unsigned short* Wc = (unsigned short*)d_ws; // 128 KB bf16 folded W
  float* bc = (float*)((char*)d_ws + (size_t)Hn * Cn * sizeof(unsigned short));

  prep_kernel<<<(Hn * Cn) / 256, 256, 0, stream>>>(Wi, bi, Wh, bh, Wc, bc);
  // 1024 blocks = 2/CU exactly, all co-resident: whole-chip load burst first,
  // one barrier, pure-register/LDS compute, store burst.
  gemm_tanh_kernel<<<1024, 512, 0, stream>>>(x, Wc, bc, out);
}

// Round 6
// 144.768 us; speedup vs baseline: 1.0035x; 1.0035x over previous
//
#include <hip/hip_runtime.h>

// hidden = tanh(x @ (Wi+Wh)^T + (bi+bh)); h_last = hidden[:, -1, :]
// GEMM M=65536 N=256 K=256 fp32 in/out, bf16 MFMA. ~134 MB floor (~21 us).
// R6: persistent pipelined streamer. R3-R5 showed register-held prefetch is
// un-forceable (allocator sinks loads; VGPR stuck at 52-64, 2.6-2.9 TB/s).
// Fix: global_load_lds DMA (zero VGPR in-flight cost) into a double-buffered
// fp32 A tile (2 x 64 KB LDS); W lives in REGISTERS (wave owns 32 cols,
// bf[2][8] = 64 VGPR, loaded once from prep-folded bf16 Wc). 1 block/CU,
// 16 waves. Per step: issue DMA for tile s+1, compute tile s (LDS->pack->
// MFMA), store, barrier (vmcnt(0) drain lands after a full compute phase).
// Chunk-XOR swizzle applied on the GLOBAL address side (LDS dest must be
// wave-uniform base + lane*16), so ds_read_b128 spreads across bank quads.

using short8 = __attribute__((ext_vector_type(8))) short;
using f32x4  = __attribute__((ext_vector_type(4))) float;

constexpr int Tn = 4096, Cn = 256, Hn = 256;
constexpr int Mn = 16 * Tn;   // 65536
constexpr int STEP = 64;      // rows per pipeline step
constexpr int RPB  = 256;     // rows per block (grid 256 = 1 block/CU)
constexpr int NSTEPS = RPB / STEP; // 4

// round-to-nearest-even fp32 -> bf16, two packed into one u32
__device__ inline unsigned pack2_bf16(float a, float b) {
  unsigned ua = __float_as_uint(a);
  unsigned ub = __float_as_uint(b);
  ua += 0x7fffu + ((ua >> 16) & 1u);
  ub += 0x7fffu + ((ub >> 16) & 1u);
  return (ua >> 16) | (ub & 0xffff0000u);
}

__global__ __launch_bounds__(256) void prep_kernel(
    const float* __restrict__ Wi, const float* __restrict__ bi,
    const float* __restrict__ Wh, const float* __restrict__ bh,
    unsigned short* __restrict__ Wc, float* __restrict__ bc) {
  int idx = blockIdx.x * 256 + threadIdx.x;
  float w = Wi[idx] + Wh[idx];
  unsigned u = __float_as_uint(w);
  u += 0x7fffu + ((u >> 16) & 1u);
  Wc[idx] = (unsigned short)(u >> 16);
  if (blockIdx.x == 0) bc[threadIdx.x] = bi[threadIdx.x] + bh[threadIdx.x];
}

// 1024 thr = 16 waves. wave = (wy: m-half of step, wx: 32-col n-slice).
__global__ __launch_bounds__(1024, 4) void gemm_tanh_kernel(
    const float* __restrict__ x, const unsigned short* __restrict__ Wc,
    const float* __restrict__ bc, float* __restrict__ out) {
  // A tile double buffer: 64 rows x 256 fp32, data placed chunk-swizzled
  // (16B chunk c of row r holds global chunk c ^ (r&7)).
  __shared__ __align__(16) float Abuf[2][STEP * Cn]; // 2 x 64 KB

  const int tid  = threadIdx.x;
  const int wave = tid >> 6;   // 0..15
  const int lane = tid & 63;
  const int rid  = lane & 15;
  const int kgrp = lane >> 4;  // 0..3
  const int wy   = wave >> 3;  // 0..1: 32-row half of the 64-row step
  const int wx   = wave & 7;   // 0..7: 32-col n-slice
  const int mBase = blockIdx.x * RPB;

  // ---- async-issue one 64-row tile: 16 waves x 4 rows x 1 KB DMA
  auto issue = [&](int s, int b) {
    const float* src = x + (size_t)(mBase + s * STEP) * Cn;
#pragma unroll
    for (int rr = 0; rr < 4; rr++) {
      int r = wave * 4 + rr;              // wave-uniform row
      int c = lane ^ (r & 7);             // swizzle on the GLOBAL side
      const float* g = src + r * Cn + c * 4;
      __builtin_amdgcn_global_load_lds(
          (const __attribute__((address_space(1))) unsigned int*)g,
          (__attribute__((address_space(3))) unsigned int*)&Abuf[b][r * Cn],
          16, 0, 0); // HW dest = uniform base + lane*16
    }
  };

  issue(0, 0); // tile 0 in flight immediately

  // ---- W fragments resident in registers for the whole kernel (64 VGPR)
  short8 bf[2][8];
  float  bias[2];
#pragma unroll
  for (int jn = 0; jn < 2; jn++) {
    int n = wx * 32 + jn * 16 + rid;
    bias[jn] = bc[n];
#pragma unroll
    for (int kc = 0; kc < 8; kc++)
      bf[jn][kc] = *(const short8*)&Wc[(size_t)n * Cn + kc * 32 + kgrp * 8];
  }
  __syncthreads(); // drains tile-0 DMA (+ W loads, already consumed)

  for (int s = 0; s < NSTEPS; s++) {
    const int b = s & 1;
    if (s + 1 < NSTEPS) issue(s + 1, b ^ 1); // DMA overlaps compute below
    __builtin_amdgcn_sched_barrier(0);       // don't sink the DMA issues

    f32x4 acc[2][2];
#pragma unroll
    for (int im = 0; im < 2; im++)
#pragma unroll
      for (int jn = 0; jn < 2; jn++) acc[im][jn] = (f32x4)0.f;

    const float* base = &Abuf[b][0];
#pragma unroll
    for (int kc = 0; kc < 8; kc++) {
      short8 af[2];
#pragma unroll
      for (int im = 0; im < 2; im++) {
        int lr = wy * 32 + im * 16 + rid;
        int c0 = kc * 8 + kgrp * 2;
        float4 v0 = *(const float4*)&base[lr * Cn + ((c0 ^ (lr & 7)) << 2)];
        float4 v1 = *(const float4*)&base[lr * Cn + (((c0 + 1) ^ (lr & 7)) << 2)];
        union { uint4 u; short8 s; } t;
        t.u.x = pack2_bf16(v0.x, v0.y);
        t.u.y = pack2_bf16(v0.z, v0.w);
        t.u.z = pack2_bf16(v1.x, v1.y);
        t.u.w = pack2_bf16(v1.z, v1.w);
        af[im] = t.s;
      }
#pragma unroll
      for (int im = 0; im < 2; im++)
#pragma unroll
        for (int jn = 0; jn < 2; jn++)
          acc[im][jn] = __builtin_amdgcn_mfma_f32_16x16x32_bf16(
              af[im], bf[jn][kc], acc[im][jn], 0, 0, 0);
    }

    // ---- epilogue: bias + tanh, store this step's 64x256 tile
#pragma unroll
    for (int im = 0; im < 2; im++)
#pragma unroll
      for (int jn = 0; jn < 2; jn++) {
        int n  = wx * 32 + jn * 16 + rid;
        int m0 = mBase + s * STEP + wy * 32 + im * 16 + kgrp * 4;
#pragma unroll
        for (int r = 0; r < 4; r++) {
          int m = m0 + r;
          float v = acc[im][jn][r] + bias[jn];
          // tanh(v) = 1 - 2/(exp(2v)+1); overflow -> 1, underflow -> -1
          float t = 1.f - 2.f / (__expf(2.f * v) + 1.f);
          out[(size_t)m * Hn + n] = t;
          if ((m & (Tn - 1)) == (Tn - 1))
            out[(size_t)Mn * Hn + (size_t)(m >> 12) * Hn + n] = t;
        }
      }

    // barrier: next DMA (issued pre-compute) has had the whole compute+store
    // phase to land -> cheap vmcnt(0) drain; also fences buf reuse.
    __syncthreads();
  }
}

extern "C" void kernel_launch(void* const* d_in, const int* in_sizes, int n_in,
                              void* d_out, int out_size, void* d_ws,
                              size_t ws_size, hipStream_t stream) {
  (void)in_sizes; (void)n_in; (void)out_size; (void)ws_size;
  const float* x  = (const float*)d_in[0];
  const float* Wi = (const float*)d_in[1];
  const float* bi = (const float*)d_in[2];
  const float* Wh = (const float*)d_in[3];
  const float* bh = (const float*)d_in[4];
  float* out = (float*)d_out;

  unsigned short* Wc = (unsigned short*)d_ws; // 128 KB bf16 folded W
  float* bc = (float*)((char*)d_ws + (size_t)Hn * Cn * sizeof(unsigned short));

  prep_kernel<<<(Hn * Cn) / 256, 256, 0, stream>>>(Wi, bi, Wh, bh, Wc, bc);
  // 256 blocks x 1024 thr = 1 block/CU, persistent 4-step pipeline each.
  gemm_tanh_kernel<<<256, 1024, 0, stream>>>(x, Wc, bc, out);
}